// Round 3
// baseline (113.222 us; speedup 1.0000x reference)
//
#include <hip/hip_runtime.h>

#define B_  16
#define SQ_ 128
#define SV_ 128
#define DQ_ 512
#define DV_ 512
#define U_  256

typedef float f32x4 __attribute__((ext_vector_type(4)));
typedef short s16x4 __attribute__((ext_vector_type(4)));

// pack two fp32 -> two RNE bf16 in one dword (low = a, high = b)
__device__ __forceinline__ unsigned pk_bf16(float a, float b) {
  unsigned ua = __float_as_uint(a); ua += 0x7fffu + ((ua >> 16) & 1u);
  unsigned ub = __float_as_uint(b); ub += 0x7fffu + ((ub >> 16) & 1u);
  return __builtin_amdgcn_perm(ub, ua, 0x07060302u);  // {hi16(ub), hi16(ua)}
}

// ---- K0: Wt[n][k] = bf16(W[k][n])  (one-time 0.5 MB transpose+convert) ----
__global__ __launch_bounds__(256) void k_prep(
    const float* __restrict__ W1, const float* __restrict__ W2,
    unsigned short* __restrict__ Wt1, unsigned short* __restrict__ Wt2)
{
  const float* __restrict__ W = blockIdx.z ? W2 : W1;
  unsigned short* __restrict__ Wt = blockIdx.z ? Wt2 : Wt1;
  __shared__ float tile[64][65];

  const int t  = threadIdx.x;
  const int k0 = blockIdx.x * 64, n0 = blockIdx.y * 64;
  const int r  = t >> 4, c4 = (t & 15) * 4;

  #pragma unroll
  for (int p = 0; p < 4; ++p) {
    f32x4 v = *(const f32x4*)&W[(k0 + p * 16 + r) * U_ + n0 + c4];
    tile[p * 16 + r][c4]     = v[0];
    tile[p * 16 + r][c4 + 1] = v[1];
    tile[p * 16 + r][c4 + 2] = v[2];
    tile[p * 16 + r][c4 + 3] = v[3];
  }
  __syncthreads();
  #pragma unroll
  for (int p = 0; p < 4; ++p) {
    int rr = p * 16 + r;
    float v0 = tile[c4][rr], v1 = tile[c4 + 1][rr];
    float v2 = tile[c4 + 2][rr], v3 = tile[c4 + 3][rr];
    uint2 o;
    o.x = pk_bf16(v0, v1);
    o.y = pk_bf16(v2, v3);
    *(uint2*)&Wt[(n0 + rr) * DQ_ + k0 + c4] = o;
  }
}

// ---- K1: E = exp(2*(X@W + b))  bf16 MFMA; wave = 32m x 16n; grid (32,8,2) ----
__global__ __launch_bounds__(256) void k_proj(
    const float* __restrict__ Q, const float* __restrict__ Vv,
    const unsigned short* __restrict__ Wt1, const float* __restrict__ b1,
    const unsigned short* __restrict__ Wt2, const float* __restrict__ b2,
    float* __restrict__ E1, float* __restrict__ E2)
{
  const int which = blockIdx.z;
  const float* __restrict__ X = which ? Vv : Q;
  const unsigned short* __restrict__ Wt = which ? Wt2 : Wt1;
  const float* __restrict__ bias = which ? b2 : b1;
  float* __restrict__ E = which ? E2 : E1;

  const int lane  = threadIdx.x & 63;
  const int wid   = threadIdx.x >> 6;
  const int row16 = lane & 15;
  const int quad  = lane >> 4;

  const int m0 = blockIdx.x * 64 + (wid >> 1) * 32;
  const int n0 = blockIdx.y * 32 + (wid & 1) * 16;

  const float* a0 = X + (size_t)(m0 + row16) * DQ_ + quad * 4;
  const float* a1 = a0 + 16 * DQ_;
  const unsigned short* bp = Wt + (size_t)(n0 + row16) * DQ_ + quad * 4;

  f32x4 acc0 = (f32x4){0.f, 0.f, 0.f, 0.f};
  f32x4 acc1 = (f32x4){0.f, 0.f, 0.f, 0.f};

  for (int k = 0; k < DQ_; k += 16) {
    f32x4 av0 = *(const f32x4*)(a0 + k);
    f32x4 av1 = *(const f32x4*)(a1 + k);
    uint2 bu  = *(const uint2*)(bp + k);
    uint2 u0, u1;
    u0.x = pk_bf16(av0[0], av0[1]); u0.y = pk_bf16(av0[2], av0[3]);
    u1.x = pk_bf16(av1[0], av1[1]); u1.y = pk_bf16(av1[2], av1[3]);
    s16x4 A0 = *(s16x4*)&u0;
    s16x4 A1 = *(s16x4*)&u1;
    s16x4 Bf = *(s16x4*)&bu;
    acc0 = __builtin_amdgcn_mfma_f32_16x16x16bf16_1k(A0, Bf, acc0, 0, 0, 0);
    acc1 = __builtin_amdgcn_mfma_f32_16x16x16bf16_1k(A1, Bf, acc1, 0, 0, 0);
  }

  const float bv = bias[n0 + row16];
  #pragma unroll
  for (int r = 0; r < 4; ++r) {
    E[(size_t)(m0 + quad * 4 + r) * U_ + n0 + row16]      = __expf(2.f * (acc0[r] + bv));
    E[(size_t)(m0 + 16 + quad * 4 + r) * U_ + n0 + row16] = __expf(2.f * (acc1[r] + bv));
  }
}

// ---- K2: score via E1*E2 + quad-paired rcp, softmax, context ----
__global__ __launch_bounds__(1024) void k_attn(
    const float* __restrict__ E1, const float* __restrict__ E2,
    const float* __restrict__ Vw, const float* __restrict__ values,
    float* __restrict__ out_ctx, float* __restrict__ out_w)
{
  __shared__ float e1s[8 * U_];   // 8 KB
  __shared__ float vws[U_];       // 1 KB
  __shared__ float part[4096];    // 16 KB
  __shared__ float red[8];

  const int tid  = threadIdx.x;
  const int lane = tid & 63;
  const int wid  = tid >> 6;
  const int b  = blockIdx.y;
  const int q0 = blockIdx.x * 8;

  if (tid < 512) {
    int q = tid >> 6, u4 = tid & 63;
    ((f32x4*)e1s)[q * 64 + u4] =
        *(const f32x4*)&E1[(size_t)(b * SQ_ + q0 + q) * U_ + u4 * 4];
  }
  if (tid < 256) vws[tid] = Vw[tid];
  __syncthreads();

  if (wid == 0) {  // Svw = sum(Vw); Vb dropped (softmax shift-invariant)
    float s = vws[lane] + vws[lane + 64] + vws[lane + 128] + vws[lane + 192];
    #pragma unroll
    for (int o = 32; o; o >>= 1) s += __shfl_xor(s, o);
    if (lane == 0) red[0] = s;
  }

  const int v5 = tid & 31;
  const int uh = (tid >> 5) & 7;
  const int vh = tid >> 8;
  const int v  = vh * 32 + v5;

  f32x4 e2r[8];
  {
    const f32x4* e2p = (const f32x4*)&E2[(size_t)(b * SV_ + v) * U_ + uh * 32];
    #pragma unroll
    for (int uq = 0; uq < 8; ++uq) e2r[uq] = e2p[uq];
  }
  const f32x4* e1v = (const f32x4*)e1s;
  const f32x4* wv4 = (const f32x4*)vws;

  float acc[8];
  #pragma unroll
  for (int q = 0; q < 8; ++q) acc[q] = 0.f;

  #pragma unroll
  for (int uq = 0; uq < 8; ++uq) {
    f32x4 e2 = e2r[uq];
    f32x4 w  = wv4[uh * 8 + uq];
    #pragma unroll
    for (int q = 0; q < 8; ++q) {
      f32x4 e1 = e1v[q * 64 + uh * 8 + uq];
      // sum_{i<4} w_i/d_i with ONE rcp:
      float d0 = fmaf(e1[0], e2[0], 1.f);
      float d1 = fmaf(e1[1], e2[1], 1.f);
      float d2 = fmaf(e1[2], e2[2], 1.f);
      float d3 = fmaf(e1[3], e2[3], 1.f);
      float p01 = d0 * d1, p23 = d2 * d3;
      float n01 = fmaf(w[0], d1, w[1] * d0);
      float n23 = fmaf(w[2], d3, w[3] * d2);
      float num = fmaf(n01, p23, n23 * p01);
      float rp  = __builtin_amdgcn_rcpf(p01 * p23);
      acc[q] = fmaf(num, rp, acc[q]);
    }
  }

  #pragma unroll
  for (int q = 0; q < 8; ++q) acc[q] += __shfl_xor(acc[q], 32);
  if (lane < 32) {
    int uhh = wid & 3;
    #pragma unroll
    for (int q = 0; q < 8; ++q) part[uhh * 1024 + q * 128 + v] = acc[q];
  }
  __syncthreads();

  {
    int q = tid >> 7, vv = tid & 127;
    float s = part[q * 128 + vv] + part[1024 + q * 128 + vv] +
              part[2048 + q * 128 + vv] + part[3072 + q * 128 + vv];
    part[q * 128 + vv] = red[0] - 2.0f * s;   // score = Svw - 2*sum(w/d)
  }
  __syncthreads();

  if (wid < 8) {  // softmax over 128 v, wave per q
    int q = wid;
    float x0 = part[q * 128 + lane], x1 = part[q * 128 + lane + 64];
    float m = fmaxf(x0, x1);
    #pragma unroll
    for (int o = 32; o; o >>= 1) m = fmaxf(m, __shfl_xor(m, o));
    float e0 = __expf(x0 - m), e1 = __expf(x1 - m);
    float ssum = e0 + e1;
    #pragma unroll
    for (int o = 32; o; o >>= 1) ssum += __shfl_xor(ssum, o);
    float inv = __fdividef(1.0f, ssum);
    e0 *= inv; e1 *= inv;
    part[q * 128 + lane] = e0;
    part[q * 128 + lane + 64] = e1;
    int wbase = (b * SQ_ + q0 + q) * SV_;
    out_w[wbase + lane] = e0;
    out_w[wbase + lane + 64] = e1;
  }
  __syncthreads();

  // context: thread owns d = tid&511, half of v; values read once
  const int d = tid & 511;
  const int h = tid >> 9;
  float c[8];
  #pragma unroll
  for (int q = 0; q < 8; ++q) c[q] = 0.f;
  const float* vb = values + (size_t)(b * SV_ + h * 64) * DV_ + d;
  for (int vl = 0; vl < 64; vl += 4) {
    f32x4 wq[8];
    #pragma unroll
    for (int q = 0; q < 8; ++q)
      wq[q] = *(const f32x4*)&part[q * 128 + h * 64 + vl];
    #pragma unroll
    for (int j = 0; j < 4; ++j) {
      float val = vb[(vl + j) * DV_];
      #pragma unroll
      for (int q = 0; q < 8; ++q) c[q] = fmaf(wq[q][j], val, c[q]);
    }
  }
  __syncthreads();
  if (h == 1) {
    #pragma unroll
    for (int q = 0; q < 8; ++q) part[q * 512 + d] = c[q];
  }
  __syncthreads();
  if (h == 0) {
    #pragma unroll
    for (int q = 0; q < 8; ++q)
      out_ctx[(size_t)(b * SQ_ + q0 + q) * DV_ + d] = c[q] + part[q * 512 + d];
  }
}

extern "C" void kernel_launch(void* const* d_in, const int* in_sizes, int n_in,
                              void* d_out, int out_size, void* d_ws, size_t ws_size,
                              hipStream_t stream) {
  (void)in_sizes; (void)n_in; (void)out_size; (void)ws_size;
  const float* Q  = (const float*)d_in[0];
  const float* Vv = (const float*)d_in[1];
  const float* W1 = (const float*)d_in[2];
  const float* b1 = (const float*)d_in[3];
  const float* W2 = (const float*)d_in[4];
  const float* b2 = (const float*)d_in[5];
  const float* Vw = (const float*)d_in[6];
  // d_in[7] = Vb: unused (softmax shift-invariant)

  float* out_ctx = (float*)d_out;                 // [16,128,512]
  float* out_w   = out_ctx + B_ * SQ_ * DV_;      // [16,128,128,1]

  float* E1 = (float*)d_ws;                       // [2048,256] f32
  float* E2 = E1 + 2048 * U_;                     // [2048,256] f32
  unsigned short* Wt1 = (unsigned short*)(E2 + 2048 * U_);  // [256,512] bf16
  unsigned short* Wt2 = Wt1 + U_ * DQ_;

  k_prep<<<dim3(8, 4, 2), 256, 0, stream>>>(W1, W2, Wt1, Wt2);
  k_proj<<<dim3(32, 8, 2), 256, 0, stream>>>(Q, Vv, Wt1, b1, Wt2, b2, E1, E2);
  k_attn<<<dim3(SQ_ / 8, B_), 1024, 0, stream>>>(E1, E2, Vw, Vv, out_ctx, out_w);
}

// Round 4
// 107.059 us; speedup vs baseline: 1.0576x; 1.0576x over previous
//
#include <hip/hip_runtime.h>

#define B_  16
#define SQ_ 128
#define SV_ 128
#define DQ_ 512
#define DV_ 512
#define U_  256

typedef float f32x4 __attribute__((ext_vector_type(4)));
typedef short s16x4 __attribute__((ext_vector_type(4)));

__device__ __forceinline__ short f2bf(float f) {
  unsigned u = __float_as_uint(f);
  u += 0x7fffu + ((u >> 16) & 1u);   // RNE to bf16
  return (short)(u >> 16);
}

// ---- K1: E = exp(2*(X@W + b))  (bf16 MFMA; wave = 32m x 16n; grid (32,8,2)) ----
__global__ __launch_bounds__(256) void k_proj(
    const float* __restrict__ Q, const float* __restrict__ Vv,
    const float* __restrict__ W1, const float* __restrict__ b1,
    const float* __restrict__ W2, const float* __restrict__ b2,
    float* __restrict__ E1, float* __restrict__ E2)
{
  const int which = blockIdx.z;
  const float* __restrict__ X    = which ? Vv : Q;
  const float* __restrict__ W    = which ? W2 : W1;
  const float* __restrict__ bias = which ? b2 : b1;
  float* __restrict__ E          = which ? E2 : E1;

  const int lane  = threadIdx.x & 63;
  const int wid   = threadIdx.x >> 6;
  const int row16 = lane & 15;
  const int quad  = lane >> 4;

  const int m0 = blockIdx.x * 64 + (wid >> 1) * 32;
  const int n0 = blockIdx.y * 32 + (wid & 1) * 16;

  f32x4 acc[2];
  acc[0] = (f32x4){0.f,0.f,0.f,0.f};
  acc[1] = (f32x4){0.f,0.f,0.f,0.f};

  for (int k0 = 0; k0 < DQ_; k0 += 16) {
    s16x4 af[2], bfr;
    #pragma unroll
    for (int mt = 0; mt < 2; ++mt) {
      f32x4 av = *(const f32x4*)&X[(m0 + mt * 16 + row16) * DQ_ + k0 + quad * 4];
      af[mt][0] = f2bf(av[0]); af[mt][1] = f2bf(av[1]);
      af[mt][2] = f2bf(av[2]); af[mt][3] = f2bf(av[3]);
    }
    #pragma unroll
    for (int j = 0; j < 4; ++j)
      bfr[j] = f2bf(W[(k0 + quad * 4 + j) * U_ + n0 + row16]);
    #pragma unroll
    for (int mt = 0; mt < 2; ++mt)
      acc[mt] = __builtin_amdgcn_mfma_f32_16x16x16bf16_1k(af[mt], bfr, acc[mt], 0, 0, 0);
  }

  float bv = bias[n0 + row16];
  #pragma unroll
  for (int mt = 0; mt < 2; ++mt)
    #pragma unroll
    for (int r = 0; r < 4; ++r) {
      float s = acc[mt][r] + bv;
      E[(size_t)(m0 + mt * 16 + quad * 4 + r) * U_ + n0 + row16] = __expf(2.0f * s);
    }
}

// ---- K2: score via E1*E2 + quad-paired rcp, softmax, context ----
// 1024 threads; thread = (v, u-slice of 32); all 8 q accumulators in registers.
__global__ __launch_bounds__(1024) void k_attn(
    const float* __restrict__ E1, const float* __restrict__ E2,
    const float* __restrict__ Vw, const float* __restrict__ values,
    float* __restrict__ out_ctx, float* __restrict__ out_w)
{
  __shared__ float e1s[8 * U_];   // 8 KB
  __shared__ float vws[U_];       // 1 KB
  __shared__ float part[4096];    // 16 KB: u-partials -> scores/weights -> ctx partials
  __shared__ float red[8];

  const int tid  = threadIdx.x;
  const int lane = tid & 63;
  const int wid  = tid >> 6;
  const int b  = blockIdx.y;
  const int q0 = blockIdx.x * 8;

  if (tid < 512) {
    int q = tid >> 6, u4 = tid & 63;
    ((f32x4*)e1s)[q * 64 + u4] =
        *(const f32x4*)&E1[(size_t)(b * SQ_ + q0 + q) * U_ + u4 * 4];
  }
  if (tid < 256) vws[tid] = Vw[tid];
  __syncthreads();

  if (wid == 0) {  // Svw = sum(Vw); Vb dropped (softmax shift-invariant)
    float s = vws[lane] + vws[lane + 64] + vws[lane + 128] + vws[lane + 192];
    #pragma unroll
    for (int o = 32; o; o >>= 1) s += __shfl_xor(s, o);
    if (lane == 0) red[0] = s;
  }

  const int v5 = tid & 31;
  const int uh = (tid >> 5) & 7;
  const int vh = tid >> 8;
  const int v  = vh * 32 + v5;

  f32x4 e2r[8];
  {
    const f32x4* e2p = (const f32x4*)&E2[(size_t)(b * SV_ + v) * U_ + uh * 32];
    #pragma unroll
    for (int uq = 0; uq < 8; ++uq) e2r[uq] = e2p[uq];
  }
  const f32x4* e1v = (const f32x4*)e1s;
  const f32x4* wv4 = (const f32x4*)vws;

  float acc[8];
  #pragma unroll
  for (int q = 0; q < 8; ++q) acc[q] = 0.f;

  #pragma unroll
  for (int uq = 0; uq < 8; ++uq) {
    f32x4 e2 = e2r[uq];
    f32x4 w  = wv4[uh * 8 + uq];
    #pragma unroll
    for (int q = 0; q < 8; ++q) {
      f32x4 e1 = e1v[q * 64 + uh * 8 + uq];
      // sum_{i<4} w_i/d_i with ONE rcp:
      float d0 = fmaf(e1[0], e2[0], 1.f);
      float d1 = fmaf(e1[1], e2[1], 1.f);
      float d2 = fmaf(e1[2], e2[2], 1.f);
      float d3 = fmaf(e1[3], e2[3], 1.f);
      float p01 = d0 * d1, p23 = d2 * d3;
      float n01 = fmaf(w[0], d1, w[1] * d0);
      float n23 = fmaf(w[2], d3, w[3] * d2);
      float num = fmaf(n01, p23, n23 * p01);
      float rp  = __builtin_amdgcn_rcpf(p01 * p23);
      acc[q] = fmaf(num, rp, acc[q]);
    }
  }

  #pragma unroll
  for (int q = 0; q < 8; ++q) acc[q] += __shfl_xor(acc[q], 32);
  if (lane < 32) {
    int uhh = wid & 3;   // wid = vh*4 + uh[2:1]
    #pragma unroll
    for (int q = 0; q < 8; ++q) part[uhh * 1024 + q * 128 + v] = acc[q];
  }
  __syncthreads();

  {
    int q = tid >> 7, vv = tid & 127;
    float s = part[q * 128 + vv] + part[1024 + q * 128 + vv] +
              part[2048 + q * 128 + vv] + part[3072 + q * 128 + vv];
    part[q * 128 + vv] = red[0] - 2.0f * s;   // score = Svw - 2*sum(w/d)
  }
  __syncthreads();

  if (wid < 8) {  // softmax over 128 v, wave per q
    int q = wid;
    float x0 = part[q * 128 + lane], x1 = part[q * 128 + lane + 64];
    float m = fmaxf(x0, x1);
    #pragma unroll
    for (int o = 32; o; o >>= 1) m = fmaxf(m, __shfl_xor(m, o));
    float e0 = __expf(x0 - m), e1 = __expf(x1 - m);
    float ssum = e0 + e1;
    #pragma unroll
    for (int o = 32; o; o >>= 1) ssum += __shfl_xor(ssum, o);
    float inv = __fdividef(1.0f, ssum);
    e0 *= inv; e1 *= inv;
    part[q * 128 + lane] = e0;
    part[q * 128 + lane + 64] = e1;
    int wbase = (b * SQ_ + q0 + q) * SV_;
    out_w[wbase + lane] = e0;
    out_w[wbase + lane + 64] = e1;
  }
  __syncthreads();

  // context: thread owns d = tid&511, half of v; values read exactly once
  const int d = tid & 511;
  const int h = tid >> 9;
  float c[8];
  #pragma unroll
  for (int q = 0; q < 8; ++q) c[q] = 0.f;
  const float* vb = values + (size_t)(b * SV_ + h * 64) * DV_ + d;
  for (int vl = 0; vl < 64; vl += 4) {
    f32x4 wq[8];
    #pragma unroll
    for (int q = 0; q < 8; ++q)
      wq[q] = *(const f32x4*)&part[q * 128 + h * 64 + vl];
    #pragma unroll
    for (int j = 0; j < 4; ++j) {
      float val = vb[(vl + j) * DV_];
      #pragma unroll
      for (int q = 0; q < 8; ++q) c[q] = fmaf(wq[q][j], val, c[q]);
    }
  }
  __syncthreads();
  if (h == 1) {
    #pragma unroll
    for (int q = 0; q < 8; ++q) part[q * 512 + d] = c[q];
  }
  __syncthreads();
  if (h == 0) {
    #pragma unroll
    for (int q = 0; q < 8; ++q)
      out_ctx[(size_t)(b * SQ_ + q0 + q) * DV_ + d] = c[q] + part[q * 512 + d];
  }
}

extern "C" void kernel_launch(void* const* d_in, const int* in_sizes, int n_in,
                              void* d_out, int out_size, void* d_ws, size_t ws_size,
                              hipStream_t stream) {
  (void)in_sizes; (void)n_in; (void)out_size; (void)ws_size;
  const float* Q  = (const float*)d_in[0];
  const float* Vv = (const float*)d_in[1];
  const float* W1 = (const float*)d_in[2];
  const float* b1 = (const float*)d_in[3];
  const float* W2 = (const float*)d_in[4];
  const float* b2 = (const float*)d_in[5];
  const float* Vw = (const float*)d_in[6];
  // d_in[7] = Vb: unused (softmax shift-invariant)

  float* out_ctx = (float*)d_out;                 // [16,128,512]
  float* out_w   = out_ctx + B_ * SQ_ * DV_;      // [16,128,128,1]

  float* E1 = (float*)d_ws;                       // [2048,256]
  float* E2 = E1 + 2048 * U_;                     // [2048,256]

  k_proj<<<dim3(32, 8, 2), 256, 0, stream>>>(Q, Vv, W1, b1, W2, b2, E1, E2);
  k_attn<<<dim3(SQ_ / 8, B_), 1024, 0, stream>>>(E1, E2, Vw, Vv, out_ctx, out_w);
}